// Round 6
// baseline (250.689 us; speedup 1.0000x reference)
//
#include <hip/hip_runtime.h>

// Problem constants
#define NIMG 32
#define PIMG (512 * 512)             // 262144 pixels per image
#define BINS 512                     // histogram bins over e in [0, 8)
#define GRID 1024                    // persistent grid: 4 blocks/CU on 256 CUs
#define BPI 32                       // blocks per image (phase 1)
#define NTHREADS 256
#define CHUNK (PIMG / BPI)           // 8192 pixels per block
#define PER_T (CHUNK / NTHREADS)     // 32 pixels per thread (8 float4 + 8 int4)
#define NB4 (PER_T / 4)              // 8
#define RBLKS 64                     // phase 2 blocks (img x half)
#define POS_PER_T (BINS / NTHREADS)  // 2 bin-positions per thread in phase 3
#define FIXED_SCALE 17592186044416.0 // 2^44

__device__ __forceinline__ float sigmoidf_(float x) {
    return __builtin_amdgcn_rcpf(1.0f + __expf(-x));
}

// Workspace layout (bytes):
//   gpart : u32 [GRID][BINS]   @ 0        2 MB  (cnt<<16 | q), fully rewritten
//   gtv   : float4 [GRID]      @ 2 MB     16 KB {tp, S, p, pad}, fully rewritten
//   ghist : u64 [NIMG][BINS]   @ +16 KB   128 KB, fully rewritten
//   sync  : u32[8] + u64[2]    @ +128 KB  48 B  {ctr0,flag0,ctr1,flag1,pad..., fxsum, done}
#define OFF_GTV   (GRID * BINS * 4)
#define OFF_GHIST (OFF_GTV + GRID * 16)
#define OFF_SYNC  (OFF_GHIST + NIMG * BINS * 8)
#define SYNC_BYTES 64

__device__ __forceinline__ void grid_barrier(unsigned* ctr, unsigned* flag) {
    __syncthreads();
    if (threadIdx.x == 0) {
        __threadfence();  // release: make this block's global writes visible device-wide
        unsigned old = __hip_atomic_fetch_add(ctr, 1u, __ATOMIC_ACQ_REL,
                                              __HIP_MEMORY_SCOPE_AGENT);
        if (old == GRID - 1) {
            __hip_atomic_store(flag, 1u, __ATOMIC_RELEASE, __HIP_MEMORY_SCOPE_AGENT);
        } else {
            while (__hip_atomic_load(flag, __ATOMIC_ACQUIRE,
                                     __HIP_MEMORY_SCOPE_AGENT) == 0u)
                __builtin_amdgcn_s_sleep(2);
        }
        __threadfence();  // acquire side before reading other blocks' data
    }
    __syncthreads();
}

__global__ __launch_bounds__(NTHREADS, 4) void fused_loss(
    const float* __restrict__ logits, const int* __restrict__ targets,
    unsigned* __restrict__ gpart, float4* __restrict__ gtv,
    unsigned long long* __restrict__ ghist, unsigned* __restrict__ syncv,
    unsigned long long* __restrict__ gacc, float* __restrict__ out) {
    __shared__ unsigned hcq[BINS];
    __shared__ float red[12];              // 4 waves x {tp, S, pc}
    __shared__ float smx[4];
    __shared__ unsigned long long wt[8];   // double-buffered wave step-totals
    __shared__ double rd[4];

    const int tid = threadIdx.x;
    const int bid = blockIdx.x;
    const int lane = tid & 63, w = tid >> 6;

    // ================= Phase 1: per-block histogram + tversky partials ========
    {
        const int img = bid >> 5;
        const int blk = bid & 31;

#pragma unroll
        for (int i = 0; i < BINS / NTHREADS; ++i) hcq[tid + i * NTHREADS] = 0u;
        __syncthreads();

        const long long base = (long long)img * PIMG + (long long)blk * CHUNK;
        const float4* lg4 = reinterpret_cast<const float4*>(logits + base);
        const int4* tg4 = reinterpret_cast<const int4*>(targets + base);

        // issue all 16 global loads up front (256 B/thread in flight)
        float4 x4[NB4];
        int4 t4[NB4];
#pragma unroll
        for (int it = 0; it < NB4; ++it) {
            x4[it] = lg4[it * NTHREADS + tid];
            t4[it] = tg4[it * NTHREADS + tid];
        }

        float tp = 0.0f, Ssum = 0.0f;
        unsigned pc = 0;
#pragma unroll
        for (int it = 0; it < NB4; ++it) {
#pragma unroll
            for (int j = 0; j < 4; ++j) {
                float x = (&x4[it].x)[j];
                int t = (&t4[it].x)[j];
                float s = sigmoidf_(x);
                Ssum += s;
                if (t) { tp += s; pc++; }
                float e = t ? (1.0f - x) : (1.0f + x);
                if (e >= 0.0f) {
                    int b = (int)(e * ((float)BINS / 8.0f));
                    if (b > BINS - 1) b = BINS - 1;
                    atomicAdd(&hcq[b], 0x10000u + (unsigned)t);
                }
            }
        }
        __syncthreads();

        // flush: one uint2 per thread, plain coalesced stores (cnt<=8192 fits fields)
        reinterpret_cast<uint2*>(gpart + (size_t)bid * BINS)[tid] =
            reinterpret_cast<const uint2*>(hcq)[tid];

        // wave shuffle reduction of tversky partials
        unsigned pcu = pc;
#pragma unroll
        for (int off = 32; off > 0; off >>= 1) {
            tp += __shfl_down(tp, off);
            Ssum += __shfl_down(Ssum, off);
            pcu += __shfl_down(pcu, off);
        }
        if (lane == 0) { red[w * 3] = tp; red[w * 3 + 1] = Ssum; red[w * 3 + 2] = (float)pcu; }
        __syncthreads();
        if (tid == 0) {
            gtv[bid] = make_float4(red[0] + red[3] + red[6] + red[9],
                                   red[1] + red[4] + red[7] + red[10],
                                   red[2] + red[5] + red[8] + red[11], 0.0f);
        }
    }

    grid_barrier(&syncv[0], &syncv[1]);

    // ================= Phase 2: reduce 32 partial hists per image =============
    if (bid < RBLKS) {
        const int img = bid >> 1;
        const int half = bid & 1;
        const int bin = half * NTHREADS + tid;
        const unsigned* basep = gpart + ((size_t)img << 5) * BINS + bin;
        unsigned c = 0, q = 0;
#pragma unroll 8
        for (int blk = 0; blk < BPI; ++blk) {
            unsigned u = basep[(size_t)blk * BINS];   // coalesced across threads
            c += (u >> 16);
            q += (u & 0xffffu);
        }
        ghist[(size_t)img * BINS + bin] =
            ((unsigned long long)c << 32) | (unsigned long long)q;
    }

    grid_barrier(&syncv[2], &syncv[3]);

    if (bid >= NIMG) return;

    // ================= Phase 3: per-image descending scan + combine ===========
    {
        const int img = bid;

        // reduce tversky partials (32 per image; wave 0)
        float4 v = make_float4(0.f, 0.f, 0.f, 0.f);
        if (tid < BPI) v = gtv[img * BPI + tid];
#pragma unroll
        for (int off = 16; off > 0; off >>= 1) {
            v.x += __shfl_down(v.x, off);
            v.y += __shfl_down(v.y, off);
            v.z += __shfl_down(v.z, off);
        }
        if (tid == 0) { smx[0] = v.x; smx[1] = v.y; smx[2] = v.z; }

        // load summed hist; thread t owns bins b = j*256 + t
        unsigned long long own[POS_PER_T];
        const unsigned long long* hb = ghist + (size_t)img * BINS;
#pragma unroll
        for (int j = 0; j < POS_PER_T; ++j) own[j] = hb[j * NTHREADS + tid];
        __syncthreads();
        const float tpv = smx[0], Sv = smx[1];
        const long long p = (long long)(smx[2] + 0.5f);
        const long long n = (long long)PIMG - p;

        // descending-e scan: steps j = 1..0
        unsigned long long runHigh = 0ull;
        double lov = 0.0;
        const double wbin = 8.0 / (double)BINS;

        for (int j = POS_PER_T - 1; j >= 0; --j) {
            const unsigned long long val = own[j];
            unsigned long long incl = val;   // wave inclusive suffix sum
#pragma unroll
            for (int off = 1; off < 64; off <<= 1) {
                unsigned long long o = __shfl_down(incl, off);
                if (lane + off < 64) incl += o;
            }
            const int buf = (j & 1) * 4;
            if (lane == 0) wt[buf + w] = incl;
            __syncthreads();
            unsigned long long higher = 0ull, stepTotal = 0ull;
#pragma unroll
            for (int w2 = 0; w2 < 4; ++w2) {
                unsigned long long tw = wt[buf + w2];
                stepTotal += tw;
                if (w2 > w) higher += tw;
            }
            const unsigned long long before = runHigh + higher + (incl - val);

            const long long g = (long long)(val >> 32);
            if (g) {
                const long long q = (long long)(val & 0xffffffffull);
                const long long N0 = (long long)(before >> 32);
                const long long C0 = (long long)(before & 0xffffffffull);
                const int bin = j * NTHREADS + tid;
                const double center = ((double)bin + 0.5) * wbin;
                const long long Ib = p - C0;        // intersection before
                const long long Ub = p + N0 - C0;   // union before
                const long long Ia = Ib - q;
                const long long Ua = Ub + g - q;
                if (n > 0) {
                    double dJ;
                    if (N0 == 0) {
                        dJ = 1.0 - (double)Ia / (double)Ua;   // telescoped first bin
                    } else {
                        const long long num = Ib * (g - q) + q * Ub;
                        dJ = (double)num / ((double)Ua * (double)Ub);
                    }
                    lov += center * dJ;
                } else {
                    const double Jafter = 1.0 - (double)Ia / (double)Ua;
                    lov += (double)g * center * Jafter;
                }
            }
            runHigh += stepTotal;
        }

        // reduce lov across block, tversky, deterministic fixed-point combine
#pragma unroll
        for (int off = 32; off > 0; off >>= 1) lov += __shfl_down(lov, off);
        if (lane == 0) rd[w] = lov;
        __syncthreads();
        if (tid == 0) {
            const double lovt = rd[0] + rd[1] + rd[2] + rd[3];
            const float pf = (float)p;
            const float fn = pf - tpv;
            const float fp_ = Sv - tpv;
            const float tv = (tpv + 1e-6f) / (tpv + 0.3f * fn + 0.7f * fp_ + 1e-6f);
            float bse = 1.0f - tv;
            if (bse < 0.0f) bse = 0.0f;
            const double contrib = ((double)powf(bse, 1.33f) + 0.2 * lovt) / (double)NIMG;
            const long long fx = (long long)(contrib * FIXED_SCALE);
            atomicAdd(&gacc[0], (unsigned long long)fx);
            __threadfence();
            const unsigned long long done = atomicAdd(&gacc[1], 1ull);
            if (done == (unsigned long long)(NIMG - 1)) {
                const unsigned long long sum = atomicAdd(&gacc[0], 0ull);
                out[0] = (float)((double)(long long)sum / FIXED_SCALE);
            }
        }
    }
}

extern "C" void kernel_launch(void* const* d_in, const int* in_sizes, int n_in,
                              void* d_out, int out_size, void* d_ws, size_t ws_size,
                              hipStream_t stream) {
    const float* logits = (const float*)d_in[0];
    const int* targets = (const int*)d_in[1];
    float* out = (float*)d_out;
    char* ws = (char*)d_ws;

    unsigned* gpart = (unsigned*)ws;
    float4* gtv = (float4*)(ws + OFF_GTV);
    unsigned long long* ghist = (unsigned long long*)(ws + OFF_GHIST);
    unsigned* syncv = (unsigned*)(ws + OFF_SYNC);
    unsigned long long* gacc = (unsigned long long*)(ws + OFF_SYNC + 32);

    // reset barrier counters/flags + fixed-point accumulator every call
    hipMemsetAsync(ws + OFF_SYNC, 0, SYNC_BYTES, stream);
    fused_loss<<<GRID, NTHREADS, 0, stream>>>(logits, targets, gpart, gtv,
                                              ghist, syncv, gacc, out);
}

// Round 7
// 25.520 us; speedup vs baseline: 9.8231x; 9.8231x over previous
//
#include <hip/hip_runtime.h>

// Problem constants
#define NIMG 32
#define PIMG (512 * 512)             // 262144 pixels per image
#define BINS 512                     // histogram bins over e in [0, 8)
#define BPI 64                       // blocks per image (kernel 1)
#define K1_THREADS 256
#define CHUNK (PIMG / BPI)           // 4096 pixels per block
#define PER_T (CHUNK / K1_THREADS)   // 16 pixels per thread (4 float4 + 4 int4)
#define NB4 (PER_T / 4)              // 4
#define K2_THREADS 256
#define K2_BLOCKS (NIMG * 2)         // (img, half) -> 256 bins each
#define K3_THREADS 256
#define POS_PER_T (BINS / K3_THREADS) // 2 bin-positions per thread
#define FIXED_SCALE 17592186044416.0  // 2^44

__device__ __forceinline__ float sigmoidf_(float x) {
    return __builtin_amdgcn_rcpf(1.0f + __expf(-x));
}

// Workspace layout (bytes) — all live regions fully rewritten each call:
//   gpart : u32 [NIMG*BPI][BINS]    @ 0          4 MB   (cnt<<16 | q)
//   gtv   : float4 [NIMG*BPI]       @ 4 MB       32 KB  {tp, S, p, pad}
//   ghist : u64 [NIMG][BINS]        @ +32 KB     128 KB (cnt<<32 | q)
//   gacc  : u64 [2]                 @ +128 KB    {fixed-point sum, done count}
#define OFF_GTV   (NIMG * BPI * BINS * 4)
#define OFF_GHIST (OFF_GTV + NIMG * BPI * 16)
#define OFF_GACC  (OFF_GHIST + NIMG * BINS * 8)

__global__ __launch_bounds__(K1_THREADS, 8) void k1_hist(
    const float* __restrict__ logits, const int* __restrict__ targets,
    unsigned* __restrict__ gpart, float4* __restrict__ gtv,
    unsigned long long* __restrict__ gacc) {
    __shared__ unsigned hcq[BINS];   // (count<<16)|q; per-block count <= 4096 fits
    __shared__ float red[12];        // 4 waves x {tp, S, pc}

    const int tid = threadIdx.x;
    const int img = blockIdx.x >> 6;
    const int blk = blockIdx.x & 63;

    // reset the cross-kernel accumulator (k3 runs later on the same stream)
    if (blockIdx.x == 0 && tid == 0) { gacc[0] = 0ull; gacc[1] = 0ull; }

#pragma unroll
    for (int i = 0; i < BINS / K1_THREADS; ++i) hcq[tid + i * K1_THREADS] = 0u;
    __syncthreads();

    const long long base = (long long)img * PIMG + (long long)blk * CHUNK;
    const float4* lg4 = reinterpret_cast<const float4*>(logits + base);
    const int4* tg4 = reinterpret_cast<const int4*>(targets + base);

    // issue all global loads up front (8 loads, 128 B/thread in flight)
    float4 x4[NB4];
    int4 t4[NB4];
#pragma unroll
    for (int it = 0; it < NB4; ++it) {
        x4[it] = lg4[it * K1_THREADS + tid];
        t4[it] = tg4[it * K1_THREADS + tid];
    }

    float tp = 0.0f, Ssum = 0.0f;
    unsigned pc = 0;

#pragma unroll
    for (int it = 0; it < NB4; ++it) {
#pragma unroll
        for (int j = 0; j < 4; ++j) {
            float x = (&x4[it].x)[j];
            int t = (&t4[it].x)[j];
            float s = sigmoidf_(x);
            Ssum += s;
            if (t) { tp += s; pc++; }
            float e = t ? (1.0f - x) : (1.0f + x);
            if (e >= 0.0f) {
                int b = (int)(e * ((float)BINS / 8.0f));
                if (b > BINS - 1) b = BINS - 1;
                atomicAdd(&hcq[b], 0x10000u + (unsigned)t);
            }
        }
    }
    __syncthreads();

    // flush histogram: one uint2 per thread, plain coalesced 8B stores
    reinterpret_cast<uint2*>(gpart + (size_t)blockIdx.x * BINS)[tid] =
        reinterpret_cast<const uint2*>(hcq)[tid];

    // wave shuffle reduction of tversky partials -> single float4 store
    unsigned pcu = pc;
#pragma unroll
    for (int off = 32; off > 0; off >>= 1) {
        tp += __shfl_down(tp, off);
        Ssum += __shfl_down(Ssum, off);
        pcu += __shfl_down(pcu, off);
    }
    const int lane = tid & 63, w = tid >> 6;
    if (lane == 0) { red[w * 3] = tp; red[w * 3 + 1] = Ssum; red[w * 3 + 2] = (float)pcu; }
    __syncthreads();
    if (tid == 0) {
        gtv[blockIdx.x] = make_float4(red[0] + red[3] + red[6] + red[9],
                                      red[1] + red[4] + red[7] + red[10],
                                      red[2] + red[5] + red[8] + red[11], 0.0f);
    }
}

// k2: reduce the 64 partial hists per image. Block (img, half): bins half*256+t.
__global__ __launch_bounds__(K2_THREADS) void k2_reduce(
    const unsigned* __restrict__ gpart, unsigned long long* __restrict__ ghist) {
    const int t = threadIdx.x;
    const int img = blockIdx.x >> 1;
    const int half = blockIdx.x & 1;
    const int bin = half * K2_THREADS + t;

    const unsigned* basep = gpart + ((size_t)img * BPI) * BINS + bin;
    unsigned c = 0, q = 0;
#pragma unroll 8
    for (int blk = 0; blk < BPI; ++blk) {
        unsigned u = basep[(size_t)blk * BINS];   // coalesced across threads
        c += (u >> 16);
        q += (u & 0xffffu);
    }
    ghist[(size_t)img * BINS + bin] = ((unsigned long long)c << 32) | (unsigned long long)q;
}

// k3: per-image descending scan + tversky + deterministic fixed-point combine.
__global__ __launch_bounds__(K3_THREADS) void k3_lovasz(
    const unsigned long long* __restrict__ ghist, const float4* __restrict__ gtv,
    unsigned long long* __restrict__ gacc, float* __restrict__ out) {
    const int img = blockIdx.x;
    const int t = threadIdx.x;
    const int lane = t & 63, w = t >> 6;

    __shared__ float smx[4];
    __shared__ unsigned long long wt[8];   // double-buffered wave step-totals
    __shared__ double rd[4];

    // ---- 1) reduce tversky partials (64 per image; wave 0 handles them) ----
    float4 v = make_float4(0.f, 0.f, 0.f, 0.f);
    if (t < 64) v = gtv[img * BPI + t];
#pragma unroll
    for (int off = 32; off > 0; off >>= 1) {
        v.x += __shfl_down(v.x, off);
        v.y += __shfl_down(v.y, off);
        v.z += __shfl_down(v.z, off);
    }
    if (t == 0) { smx[0] = v.x; smx[1] = v.y; smx[2] = v.z; }

    // ---- 2) load summed hist; thread t owns bins b = j*256 + t ----
    unsigned long long own[POS_PER_T];
    const unsigned long long* hb = ghist + (size_t)img * BINS;
#pragma unroll
    for (int j = 0; j < POS_PER_T; ++j) own[j] = hb[j * K3_THREADS + t];
    __syncthreads();
    const float tpv = smx[0], Sv = smx[1];
    const long long p = (long long)(smx[2] + 0.5f);
    const long long n = (long long)PIMG - p;

    // ---- 3) descending-e scan: steps j = 1..0 (bin j*256+t; larger bin = larger e) ----
    unsigned long long runHigh = 0ull;  // totals of all bins above current step
    double lov = 0.0;
    const double wbin = 8.0 / (double)BINS;

    for (int j = POS_PER_T - 1; j >= 0; --j) {
        const unsigned long long val = own[j];
        // wave inclusive suffix sum: incl[t] = sum_{t'>=t in wave} val[t']
        unsigned long long incl = val;
#pragma unroll
        for (int off = 1; off < 64; off <<= 1) {
            unsigned long long o = __shfl_down(incl, off);
            if (lane + off < 64) incl += o;
        }
        const int buf = (j & 1) * 4;
        if (lane == 0) wt[buf + w] = incl;
        __syncthreads();
        unsigned long long higher = 0ull, stepTotal = 0ull;
#pragma unroll
        for (int w2 = 0; w2 < 4; ++w2) {
            unsigned long long tw = wt[buf + w2];
            stepTotal += tw;
            if (w2 > w) higher += tw;
        }
        const unsigned long long before = runHigh + higher + (incl - val);

        const long long g = (long long)(val >> 32);
        if (g) {
            const long long q = (long long)(val & 0xffffffffull);
            const long long N0 = (long long)(before >> 32);
            const long long C0 = (long long)(before & 0xffffffffull);
            const int bin = j * K3_THREADS + t;
            const double center = ((double)bin + 0.5) * wbin;
            const long long Ib = p - C0;        // intersection before
            const long long Ub = p + N0 - C0;   // union before
            const long long Ia = Ib - q;
            const long long Ua = Ub + g - q;
            if (n > 0) {
                double dJ;
                if (N0 == 0) {
                    // sum of grads over first bin telescopes to J_after
                    dJ = 1.0 - (double)Ia / (double)Ua;
                } else {
                    // J_after - J_before = (Ib*(g-q) + q*Ub) / (Ua*Ub)
                    const long long num = Ib * (g - q) + q * Ub;
                    dJ = (double)num / ((double)Ua * (double)Ub);
                }
                lov += center * dJ;
            } else {
                const double Jafter = 1.0 - (double)Ia / (double)Ua;
                lov += (double)g * center * Jafter;
            }
        }
        runHigh += stepTotal;
    }

    // ---- 4) reduce lov across block, combine, fixed-point atomic accumulate ----
#pragma unroll
    for (int off = 32; off > 0; off >>= 1) lov += __shfl_down(lov, off);
    if (lane == 0) rd[w] = lov;
    __syncthreads();
    if (t == 0) {
        const double lovt = rd[0] + rd[1] + rd[2] + rd[3];
        const float pf = (float)p;
        const float fn = pf - tpv;
        const float fp_ = Sv - tpv;
        const float tv = (tpv + 1e-6f) / (tpv + 0.3f * fn + 0.7f * fp_ + 1e-6f);
        float bse = 1.0f - tv;
        if (bse < 0.0f) bse = 0.0f;
        const double contrib = ((double)powf(bse, 1.33f) + 0.2 * lovt) / (double)NIMG;
        const long long fx = (long long)(contrib * FIXED_SCALE);
        atomicAdd(&gacc[0], (unsigned long long)fx);
        __threadfence();
        const unsigned long long done = atomicAdd(&gacc[1], 1ull);
        if (done == (unsigned long long)(NIMG - 1)) {
            const unsigned long long sum = atomicAdd(&gacc[0], 0ull);  // coherent read
            out[0] = (float)((double)(long long)sum / FIXED_SCALE);
        }
    }
}

extern "C" void kernel_launch(void* const* d_in, const int* in_sizes, int n_in,
                              void* d_out, int out_size, void* d_ws, size_t ws_size,
                              hipStream_t stream) {
    const float* logits = (const float*)d_in[0];
    const int* targets = (const int*)d_in[1];
    float* out = (float*)d_out;
    char* ws = (char*)d_ws;

    unsigned* gpart = (unsigned*)ws;
    float4* gtv = (float4*)(ws + OFF_GTV);
    unsigned long long* ghist = (unsigned long long*)(ws + OFF_GHIST);
    unsigned long long* gacc = (unsigned long long*)(ws + OFF_GACC);

    k1_hist<<<NIMG * BPI, K1_THREADS, 0, stream>>>(logits, targets, gpart, gtv, gacc);
    k2_reduce<<<K2_BLOCKS, K2_THREADS, 0, stream>>>(gpart, ghist);
    k3_lovasz<<<NIMG, K3_THREADS, 0, stream>>>(ghist, gtv, gacc, out);
}

// Round 8
// 24.664 us; speedup vs baseline: 10.1643x; 1.0347x over previous
//
#include <hip/hip_runtime.h>

// Problem constants
#define NIMG 32
#define PIMG (512 * 512)             // 262144 pixels per image
#define BINS 512                     // histogram bins over e in [0, 8)
#define BPI 64                       // blocks per image (kernel 1)
#define K1_THREADS 256
#define CHUNK (PIMG / BPI)           // 4096 pixels per block
#define PER_T (CHUNK / K1_THREADS)   // 16 pixels per thread (4 float4 + 4 int4)
#define NB4 (PER_T / 4)              // 4
#define K2_THREADS 256
#define POS_PER_T (BINS / K2_THREADS) // 2 bin-positions per thread
#define FIXED_SCALE 17592186044416.0  // 2^44

__device__ __forceinline__ float sigmoidf_(float x) {
    return __builtin_amdgcn_rcpf(1.0f + __expf(-x));
}

// Workspace layout (bytes) — all live regions fully rewritten each call:
//   gpart : u32 [NIMG*BPI][BINS]    @ 0          4 MB   (cnt<<16 | q)
//   gtv   : float4 [NIMG*BPI]       @ 4 MB       32 KB  {tp, S, p, pad}
//   gacc  : u64 [2]                 @ +32 KB     {fixed-point sum, done count}
#define OFF_GTV   (NIMG * BPI * BINS * 4)
#define OFF_GACC  (OFF_GTV + NIMG * BPI * 16)

__global__ __launch_bounds__(K1_THREADS, 8) void k1_hist(
    const float* __restrict__ logits, const int* __restrict__ targets,
    unsigned* __restrict__ gpart, float4* __restrict__ gtv,
    unsigned long long* __restrict__ gacc) {
    __shared__ unsigned hcq[BINS];   // (count<<16)|q; per-block count <= 4096 fits
    __shared__ float red[12];        // 4 waves x {tp, S, pc}

    const int tid = threadIdx.x;
    const int img = blockIdx.x >> 6;
    const int blk = blockIdx.x & 63;

    // reset the cross-kernel accumulator (k23 runs later on the same stream)
    if (blockIdx.x == 0 && tid == 0) { gacc[0] = 0ull; gacc[1] = 0ull; }

#pragma unroll
    for (int i = 0; i < BINS / K1_THREADS; ++i) hcq[tid + i * K1_THREADS] = 0u;
    __syncthreads();

    const long long base = (long long)img * PIMG + (long long)blk * CHUNK;
    const float4* lg4 = reinterpret_cast<const float4*>(logits + base);
    const int4* tg4 = reinterpret_cast<const int4*>(targets + base);

    // issue all global loads up front (8 loads, 128 B/thread in flight)
    float4 x4[NB4];
    int4 t4[NB4];
#pragma unroll
    for (int it = 0; it < NB4; ++it) {
        x4[it] = lg4[it * K1_THREADS + tid];
        t4[it] = tg4[it * K1_THREADS + tid];
    }

    float tp = 0.0f, Ssum = 0.0f;
    unsigned pc = 0;

#pragma unroll
    for (int it = 0; it < NB4; ++it) {
#pragma unroll
        for (int j = 0; j < 4; ++j) {
            float x = (&x4[it].x)[j];
            int t = (&t4[it].x)[j];
            float s = sigmoidf_(x);
            Ssum += s;
            if (t) { tp += s; pc++; }
            float e = t ? (1.0f - x) : (1.0f + x);
            if (e >= 0.0f) {
                int b = (int)(e * ((float)BINS / 8.0f));
                if (b > BINS - 1) b = BINS - 1;
                atomicAdd(&hcq[b], 0x10000u + (unsigned)t);
            }
        }
    }
    __syncthreads();

    // flush histogram: one uint2 per thread, plain coalesced 8B stores
    reinterpret_cast<uint2*>(gpart + (size_t)blockIdx.x * BINS)[tid] =
        reinterpret_cast<const uint2*>(hcq)[tid];

    // wave shuffle reduction of tversky partials -> single float4 store
    unsigned pcu = pc;
#pragma unroll
    for (int off = 32; off > 0; off >>= 1) {
        tp += __shfl_down(tp, off);
        Ssum += __shfl_down(Ssum, off);
        pcu += __shfl_down(pcu, off);
    }
    const int lane = tid & 63, w = tid >> 6;
    if (lane == 0) { red[w * 3] = tp; red[w * 3 + 1] = Ssum; red[w * 3 + 2] = (float)pcu; }
    __syncthreads();
    if (tid == 0) {
        gtv[blockIdx.x] = make_float4(red[0] + red[3] + red[6] + red[9],
                                      red[1] + red[4] + red[7] + red[10],
                                      red[2] + red[5] + red[8] + red[11], 0.0f);
    }
}

// k23: per image (one block each): reduce the 64 partial hists from gpart,
// then descending scan + tversky + deterministic fixed-point combine.
__global__ __launch_bounds__(K2_THREADS) void k23_lovasz(
    const unsigned* __restrict__ gpart, const float4* __restrict__ gtv,
    unsigned long long* __restrict__ gacc, float* __restrict__ out) {
    const int img = blockIdx.x;
    const int t = threadIdx.x;
    const int lane = t & 63, w = t >> 6;

    __shared__ float smx[4];
    __shared__ unsigned long long wt[8];   // double-buffered wave step-totals
    __shared__ double rd[4];

    // ---- 1) reduce 64 partial hists; thread t owns bins {t, 256+t} ----
    unsigned c0 = 0, q0 = 0, c1 = 0, q1 = 0;
    const unsigned* basep = gpart + ((size_t)img * BPI) * BINS;
#pragma unroll 8
    for (int blk = 0; blk < BPI; ++blk) {
        const unsigned* row = basep + (size_t)blk * BINS;
        unsigned u0 = row[t];                 // coalesced across threads
        unsigned u1 = row[K2_THREADS + t];    // coalesced across threads
        c0 += (u0 >> 16); q0 += (u0 & 0xffffu);
        c1 += (u1 >> 16); q1 += (u1 & 0xffffu);
    }
    unsigned long long own[POS_PER_T];
    own[0] = ((unsigned long long)c0 << 32) | (unsigned long long)q0;
    own[1] = ((unsigned long long)c1 << 32) | (unsigned long long)q1;

    // ---- 2) reduce tversky partials (64 per image; wave 0 handles them) ----
    float4 v = make_float4(0.f, 0.f, 0.f, 0.f);
    if (t < 64) v = gtv[img * BPI + t];
#pragma unroll
    for (int off = 32; off > 0; off >>= 1) {
        v.x += __shfl_down(v.x, off);
        v.y += __shfl_down(v.y, off);
        v.z += __shfl_down(v.z, off);
    }
    if (t == 0) { smx[0] = v.x; smx[1] = v.y; smx[2] = v.z; }
    __syncthreads();
    const float tpv = smx[0], Sv = smx[1];
    const long long p = (long long)(smx[2] + 0.5f);
    const long long n = (long long)PIMG - p;

    // ---- 3) descending-e scan: steps j = 1..0 (bin j*256+t) ----
    unsigned long long runHigh = 0ull;  // totals of all bins above current step
    double lov = 0.0;
    const double wbin = 8.0 / (double)BINS;

    for (int j = POS_PER_T - 1; j >= 0; --j) {
        const unsigned long long val = own[j];
        // wave inclusive suffix sum: incl[t] = sum_{t'>=t in wave} val[t']
        unsigned long long incl = val;
#pragma unroll
        for (int off = 1; off < 64; off <<= 1) {
            unsigned long long o = __shfl_down(incl, off);
            if (lane + off < 64) incl += o;
        }
        const int buf = (j & 1) * 4;
        if (lane == 0) wt[buf + w] = incl;
        __syncthreads();
        unsigned long long higher = 0ull, stepTotal = 0ull;
#pragma unroll
        for (int w2 = 0; w2 < 4; ++w2) {
            unsigned long long tw = wt[buf + w2];
            stepTotal += tw;
            if (w2 > w) higher += tw;
        }
        const unsigned long long before = runHigh + higher + (incl - val);

        const long long g = (long long)(val >> 32);
        if (g) {
            const long long q = (long long)(val & 0xffffffffull);
            const long long N0 = (long long)(before >> 32);
            const long long C0 = (long long)(before & 0xffffffffull);
            const int bin = j * K2_THREADS + t;
            const double center = ((double)bin + 0.5) * wbin;
            const long long Ib = p - C0;        // intersection before
            const long long Ub = p + N0 - C0;   // union before
            const long long Ia = Ib - q;
            const long long Ua = Ub + g - q;
            if (n > 0) {
                double dJ;
                if (N0 == 0) {
                    // sum of grads over first bin telescopes to J_after
                    dJ = 1.0 - (double)Ia / (double)Ua;
                } else {
                    // J_after - J_before = (Ib*(g-q) + q*Ub) / (Ua*Ub)
                    const long long num = Ib * (g - q) + q * Ub;
                    dJ = (double)num / ((double)Ua * (double)Ub);
                }
                lov += center * dJ;
            } else {
                const double Jafter = 1.0 - (double)Ia / (double)Ua;
                lov += (double)g * center * Jafter;
            }
        }
        runHigh += stepTotal;
    }

    // ---- 4) reduce lov across block, combine, fixed-point atomic accumulate ----
#pragma unroll
    for (int off = 32; off > 0; off >>= 1) lov += __shfl_down(lov, off);
    if (lane == 0) rd[w] = lov;
    __syncthreads();
    if (t == 0) {
        const double lovt = rd[0] + rd[1] + rd[2] + rd[3];
        const float pf = (float)p;
        const float fn = pf - tpv;
        const float fp_ = Sv - tpv;
        const float tv = (tpv + 1e-6f) / (tpv + 0.3f * fn + 0.7f * fp_ + 1e-6f);
        float bse = 1.0f - tv;
        if (bse < 0.0f) bse = 0.0f;
        const double contrib = ((double)powf(bse, 1.33f) + 0.2 * lovt) / (double)NIMG;
        const long long fx = (long long)(contrib * FIXED_SCALE);
        atomicAdd(&gacc[0], (unsigned long long)fx);
        __threadfence();
        const unsigned long long done = atomicAdd(&gacc[1], 1ull);
        if (done == (unsigned long long)(NIMG - 1)) {
            const unsigned long long sum = atomicAdd(&gacc[0], 0ull);  // coherent read
            out[0] = (float)((double)(long long)sum / FIXED_SCALE);
        }
    }
}

extern "C" void kernel_launch(void* const* d_in, const int* in_sizes, int n_in,
                              void* d_out, int out_size, void* d_ws, size_t ws_size,
                              hipStream_t stream) {
    const float* logits = (const float*)d_in[0];
    const int* targets = (const int*)d_in[1];
    float* out = (float*)d_out;
    char* ws = (char*)d_ws;

    unsigned* gpart = (unsigned*)ws;
    float4* gtv = (float4*)(ws + OFF_GTV);
    unsigned long long* gacc = (unsigned long long*)(ws + OFF_GACC);

    k1_hist<<<NIMG * BPI, K1_THREADS, 0, stream>>>(logits, targets, gpart, gtv, gacc);
    k23_lovasz<<<NIMG, K2_THREADS, 0, stream>>>(gpart, gtv, gacc, out);
}

// Round 9
// 23.529 us; speedup vs baseline: 10.6546x; 1.0482x over previous
//
#include <hip/hip_runtime.h>

// Problem constants
#define NIMG 32
#define PIMG (512 * 512)             // 262144 pixels per image
#define BINS 512                     // histogram bins over e in [0, 8)
#define BPI 64                       // blocks per image (kernel 1)
#define K1_THREADS 256
#define CHUNK (PIMG / BPI)           // 4096 pixels per block
#define PER_T (CHUNK / K1_THREADS)   // 16 pixels per thread (4 float4 + 4 int4)
#define NB4 (PER_T / 4)              // 4
#define K23_THREADS 1024
#define QROWS (BPI / 4)              // 16 partial hists per quarter-block
#define FIXED_SCALE 17592186044416.0  // 2^44

__device__ __forceinline__ float sigmoidf_(float x) {
    return __builtin_amdgcn_rcpf(1.0f + __expf(-x));
}

// Workspace layout (bytes) — all live regions fully rewritten each call:
//   gpart : u32 [NIMG*BPI][BINS]    @ 0          4 MB   (cnt<<16 | q)
//   gtv   : float4 [NIMG*BPI]       @ 4 MB       32 KB  {tp, S, p, pad}
//   gacc  : u64 [2]                 @ +32 KB     {fixed-point sum, done count}
#define OFF_GTV   (NIMG * BPI * BINS * 4)
#define OFF_GACC  (OFF_GTV + NIMG * BPI * 16)

__global__ __launch_bounds__(K1_THREADS, 4) void k1_hist(
    const float* __restrict__ logits, const int* __restrict__ targets,
    unsigned* __restrict__ gpart, float4* __restrict__ gtv,
    unsigned long long* __restrict__ gacc) {
    __shared__ unsigned hcq[BINS];   // (count<<16)|q; per-block count <= 4096 fits
    __shared__ float red[12];        // 4 waves x {tp, S, pc}

    const int tid = threadIdx.x;
    const int img = blockIdx.x >> 6;
    const int blk = blockIdx.x & 63;

    // reset the cross-kernel accumulator (k23 runs later on the same stream)
    if (blockIdx.x == 0 && tid == 0) { gacc[0] = 0ull; gacc[1] = 0ull; }

#pragma unroll
    for (int i = 0; i < BINS / K1_THREADS; ++i) hcq[tid + i * K1_THREADS] = 0u;
    __syncthreads();

    const long long base = (long long)img * PIMG + (long long)blk * CHUNK;
    const float4* lg4 = reinterpret_cast<const float4*>(logits + base);
    const int4* tg4 = reinterpret_cast<const int4*>(targets + base);

    // issue all global loads up front (8 loads, 128 B/thread in flight;
    // launch_bounds(256,4) gives the 128-VGPR budget so they STAY in flight)
    float4 x4[NB4];
    int4 t4[NB4];
#pragma unroll
    for (int it = 0; it < NB4; ++it) {
        x4[it] = lg4[it * K1_THREADS + tid];
        t4[it] = tg4[it * K1_THREADS + tid];
    }

    float tp = 0.0f, Ssum = 0.0f;
    unsigned pc = 0;

#pragma unroll
    for (int it = 0; it < NB4; ++it) {
#pragma unroll
        for (int j = 0; j < 4; ++j) {
            float x = (&x4[it].x)[j];
            int t = (&t4[it].x)[j];
            float s = sigmoidf_(x);
            Ssum += s;
            if (t) { tp += s; pc++; }
            float e = t ? (1.0f - x) : (1.0f + x);
            if (e >= 0.0f) {
                int b = (int)(e * ((float)BINS / 8.0f));
                if (b > BINS - 1) b = BINS - 1;
                atomicAdd(&hcq[b], 0x10000u + (unsigned)t);
            }
        }
    }
    __syncthreads();

    // flush histogram: one uint2 per thread, plain coalesced 8B stores
    reinterpret_cast<uint2*>(gpart + (size_t)blockIdx.x * BINS)[tid] =
        reinterpret_cast<const uint2*>(hcq)[tid];

    // wave shuffle reduction of tversky partials -> single float4 store
    unsigned pcu = pc;
#pragma unroll
    for (int off = 32; off > 0; off >>= 1) {
        tp += __shfl_down(tp, off);
        Ssum += __shfl_down(Ssum, off);
        pcu += __shfl_down(pcu, off);
    }
    const int lane = tid & 63, w = tid >> 6;
    if (lane == 0) { red[w * 3] = tp; red[w * 3 + 1] = Ssum; red[w * 3 + 2] = (float)pcu; }
    __syncthreads();
    if (tid == 0) {
        gtv[blockIdx.x] = make_float4(red[0] + red[3] + red[6] + red[9],
                                      red[1] + red[4] + red[7] + red[10],
                                      red[2] + red[5] + red[8] + red[11], 0.0f);
    }
}

// k23: one 1024-thread block per image. Quarter q reduces partial hists
// [q*16, q*16+16) into LDS; combine; then waves 0-3 run the descending scan.
__global__ __launch_bounds__(K23_THREADS, 4) void k23_lovasz(
    const unsigned* __restrict__ gpart, const float4* __restrict__ gtv,
    unsigned long long* __restrict__ gacc, float* __restrict__ out) {
    const int img = blockIdx.x;
    const int t = threadIdx.x;
    const int tq = t & 255;          // bin lane
    const int qt = t >> 8;           // quarter 0..3
    const int lane = t & 63, w = t >> 6;

    __shared__ unsigned long long lh[4][BINS];   // 16 KB quarter partials
    __shared__ float smx[4];
    __shared__ unsigned long long wt[8];         // double-buffered wave step-totals
    __shared__ double rd[4];

    // ---- 1) each quarter reduces its 16 partial hists (coalesced reads) ----
    unsigned c0 = 0, q0 = 0, c1 = 0, q1 = 0;
    const unsigned* basep = gpart + ((size_t)img * BPI + (size_t)qt * QROWS) * BINS;
#pragma unroll
    for (int k = 0; k < QROWS; ++k) {
        const unsigned* row = basep + (size_t)k * BINS;
        unsigned u0 = row[tq];
        unsigned u1 = row[256 + tq];
        c0 += (u0 >> 16); q0 += (u0 & 0xffffu);
        c1 += (u1 >> 16); q1 += (u1 & 0xffffu);
    }
    lh[qt][tq]       = ((unsigned long long)c0 << 32) | (unsigned long long)q0;
    lh[qt][256 + tq] = ((unsigned long long)c1 << 32) | (unsigned long long)q1;

    // ---- 2) tversky partials (64 per image; wave 0) ----
    float4 v = make_float4(0.f, 0.f, 0.f, 0.f);
    if (t < 64) v = gtv[img * BPI + t];
    if (t < 64) {
#pragma unroll
        for (int off = 32; off > 0; off >>= 1) {
            v.x += __shfl_down(v.x, off);
            v.y += __shfl_down(v.y, off);
            v.z += __shfl_down(v.z, off);
        }
    }
    if (t == 0) { smx[0] = v.x; smx[1] = v.y; smx[2] = v.z; }
    __syncthreads();

    // ---- 3) combine quarters; thread tq (t<256) owns bins {tq, 256+tq} ----
    unsigned long long own[2] = {0ull, 0ull};
    if (t < 256) {
        own[0] = lh[0][tq] + lh[1][tq] + lh[2][tq] + lh[3][tq];
        own[1] = lh[0][256 + tq] + lh[1][256 + tq] + lh[2][256 + tq] + lh[3][256 + tq];
    }
    const float tpv = smx[0], Sv = smx[1];
    const long long p = (long long)(smx[2] + 0.5f);
    const long long n = (long long)PIMG - p;

    // ---- 4) descending-e scan over 512 bins (waves 0-3; others hit barriers) ----
    unsigned long long runHigh = 0ull;
    double lov = 0.0;
    const double wbin = 8.0 / (double)BINS;

    for (int j = 1; j >= 0; --j) {
        unsigned long long val = 0ull, incl = 0ull;
        if (t < 256) {
            val = own[j];
            incl = val;   // wave inclusive suffix sum
#pragma unroll
            for (int off = 1; off < 64; off <<= 1) {
                unsigned long long o = __shfl_down(incl, off);
                if (lane + off < 64) incl += o;
            }
            if (lane == 0) wt[(j & 1) * 4 + w] = incl;
        }
        __syncthreads();
        if (t < 256) {
            const int buf = (j & 1) * 4;
            unsigned long long higher = 0ull, stepTotal = 0ull;
#pragma unroll
            for (int w2 = 0; w2 < 4; ++w2) {
                unsigned long long tw = wt[buf + w2];
                stepTotal += tw;
                if (w2 > w) higher += tw;
            }
            const unsigned long long before = runHigh + higher + (incl - val);

            const long long g = (long long)(val >> 32);
            if (g) {
                const long long q = (long long)(val & 0xffffffffull);
                const long long N0 = (long long)(before >> 32);
                const long long C0 = (long long)(before & 0xffffffffull);
                const int bin = j * 256 + tq;
                const double center = ((double)bin + 0.5) * wbin;
                const long long Ib = p - C0;        // intersection before
                const long long Ub = p + N0 - C0;   // union before
                const long long Ia = Ib - q;
                const long long Ua = Ub + g - q;
                if (n > 0) {
                    double dJ;
                    if (N0 == 0) {
                        // sum of grads over first bin telescopes to J_after
                        dJ = 1.0 - (double)Ia / (double)Ua;
                    } else {
                        // J_after - J_before = (Ib*(g-q) + q*Ub) / (Ua*Ub)
                        const long long num = Ib * (g - q) + q * Ub;
                        dJ = (double)num / ((double)Ua * (double)Ub);
                    }
                    lov += center * dJ;
                } else {
                    const double Jafter = 1.0 - (double)Ia / (double)Ua;
                    lov += (double)g * center * Jafter;
                }
            }
            runHigh += stepTotal;
        }
    }

    // ---- 5) reduce lov across waves 0-3, combine, fixed-point accumulate ----
    if (t < 256) {
#pragma unroll
        for (int off = 32; off > 0; off >>= 1) lov += __shfl_down(lov, off);
        if (lane == 0) rd[w] = lov;
    }
    __syncthreads();
    if (t == 0) {
        const double lovt = rd[0] + rd[1] + rd[2] + rd[3];
        const float pf = (float)p;
        const float fn = pf - tpv;
        const float fp_ = Sv - tpv;
        const float tv = (tpv + 1e-6f) / (tpv + 0.3f * fn + 0.7f * fp_ + 1e-6f);
        float bse = 1.0f - tv;
        if (bse < 0.0f) bse = 0.0f;
        const double contrib = ((double)powf(bse, 1.33f) + 0.2 * lovt) / (double)NIMG;
        const long long fx = (long long)(contrib * FIXED_SCALE);
        atomicAdd(&gacc[0], (unsigned long long)fx);
        __threadfence();
        const unsigned long long done = atomicAdd(&gacc[1], 1ull);
        if (done == (unsigned long long)(NIMG - 1)) {
            const unsigned long long sum = atomicAdd(&gacc[0], 0ull);  // coherent read
            out[0] = (float)((double)(long long)sum / FIXED_SCALE);
        }
    }
}

extern "C" void kernel_launch(void* const* d_in, const int* in_sizes, int n_in,
                              void* d_out, int out_size, void* d_ws, size_t ws_size,
                              hipStream_t stream) {
    const float* logits = (const float*)d_in[0];
    const int* targets = (const int*)d_in[1];
    float* out = (float*)d_out;
    char* ws = (char*)d_ws;

    unsigned* gpart = (unsigned*)ws;
    float4* gtv = (float4*)(ws + OFF_GTV);
    unsigned long long* gacc = (unsigned long long*)(ws + OFF_GACC);

    k1_hist<<<NIMG * BPI, K1_THREADS, 0, stream>>>(logits, targets, gpart, gtv, gacc);
    k23_lovasz<<<NIMG, K23_THREADS, 0, stream>>>(gpart, gtv, gacc, out);
}